// Round 1
// 906.440 us; speedup vs baseline: 1.0344x; 1.0344x over previous
//
#include <hip/hip_runtime.h>

// ---------------------------------------------------------------------------
// ModifiedTransformerEncoderLayer on MI355X (gfx950)
// B=4096 J=17 D=512 H=8 DK=64, M=B*J=69632. I/O f32; compute bf16 MFMA.
//
// Round 5 (this round): gemm_bt restructured:
//  (1) triple-buffered LDS (3x16KB) + counted s_waitcnt vmcnt(4) + raw
//      s_barrier -> removes the per-tile vmcnt(0) drain of the 2-barrier
//      m97 structure; staging for tile t+2 overlaps compute of tile t.
//  (2) XCD-aware bijective block swizzle + row-major tile order (A-panel
//      L2 reuse; grid sizes all divisible by 8).
//  (3) LDS 16B-chunk XOR swizzle kc ^= (row>>1)&3, implemented as
//      inverse-swizzled per-lane GLOBAL source addresses (gload_lds dest
//      must stay linear) + swizzled ds_read addresses. Kills the ~8-way
//      bank conflict on ds_read_b128 (1.34e7 conflict cycles/dispatch).
//
// ws layout (peak 0x11400000 = 276.1 MiB):
//   WT1 @0x000000  WT2 @0x180000  WT3 @0x200000  smalls @0x300000
//   SRCB @0x0400000 ; QKV @0x4800000 ; O @0x0400000 (SRCB dead)
//   ATT @0x4800000 (QKV dead) ; X @0x8C00000 ; H01 @0x0400000 (O/ATT dead)
// ---------------------------------------------------------------------------

typedef __attribute__((ext_vector_type(4))) float floatx4;
typedef __attribute__((ext_vector_type(8))) short short8;

#define AS1 __attribute__((address_space(1)))
#define AS3 __attribute__((address_space(3)))

__device__ __forceinline__ float bf2f(unsigned short u) {
  union { unsigned int i; float f; } x;
  x.i = ((unsigned int)u) << 16;
  return x.f;
}

__device__ __forceinline__ unsigned short f2bf(float f) {
  union { float f; unsigned int i; } x;
  x.f = f;
  unsigned int r = x.i + 0x7fffu + ((x.i >> 16) & 1u);  // RNE
  return (unsigned short)(r >> 16);
}

__device__ __forceinline__ void unpack8(uint4 u, float* f) {
  unsigned int uu[4] = {u.x, u.y, u.z, u.w};
#pragma unroll
  for (int i = 0; i < 4; ++i) {
    f[2 * i]     = bf2f((unsigned short)(uu[i] & 0xffffu));
    f[2 * i + 1] = bf2f((unsigned short)(uu[i] >> 16));
  }
}

__device__ __forceinline__ uint4 pack8(const float* f) {
  unsigned int uu[4];
#pragma unroll
  for (int i = 0; i < 4; ++i)
    uu[i] = (unsigned int)f2bf(f[2 * i]) | ((unsigned int)f2bf(f[2 * i + 1]) << 16);
  uint4 u; u.x = uu[0]; u.y = uu[1]; u.z = uu[2]; u.w = uu[3];
  return u;
}

__device__ __forceinline__ float wave_sum(float v) {
#pragma unroll
  for (int m = 1; m < 64; m <<= 1) v += __shfl_xor(v, m, 64);
  return v;
}

// async global->LDS, 16B/lane; LDS dest = wave-uniform base + lane*16
__device__ __forceinline__ void gload_lds16(const unsigned short* g, AS3 char* l) {
  __builtin_amdgcn_global_load_lds((const AS1 void*)g, (AS3 void*)l, 16, 0, 0);
}

// ---------------------------------------------------------------------------
// src f32 -> bf16, 8 elems/thread
// ---------------------------------------------------------------------------
__global__ __launch_bounds__(256) void convert_src(
    const float* __restrict__ in, unsigned short* __restrict__ out) {
  const size_t i = ((size_t)blockIdx.x * 256 + threadIdx.x) * 8;
  const float4 a = *(const float4*)(in + i);
  const float4 b = *(const float4*)(in + i + 4);
  const float f[8] = {a.x, a.y, a.z, a.w, b.x, b.y, b.z, b.w};
  *(uint4*)(out + i) = pack8(f);
}

// ---------------------------------------------------------------------------
// GEMM: C[M,N] = A[M,512] @ BT[N,512]^T (+ bias[N]), bf16 in/out, f32 accum.
// 128x128 tile, BK=32, 4 waves of 4x4 16x16x32 MFMA.
// Triple-buffered async LDS staging, counted vmcnt, raw s_barrier.
// Launch with 1-D grid = (M/128)*(N/128), divisible by 8.
// ---------------------------------------------------------------------------
__global__ __launch_bounds__(256) void gemm_bt(
    const unsigned short* __restrict__ A,
    const unsigned short* __restrict__ BT,
    const float* __restrict__ bias,
    unsigned short* __restrict__ C, int N) {
  __shared__ unsigned short As[3][128 * 32];
  __shared__ unsigned short Bs[3][128 * 32];
  const int t = threadIdx.x;
  const int wave = t >> 6;
  const int lane = t & 63;
  const int wm = wave >> 1, wn = wave & 1;

  // XCD-aware bijective swizzle (gridDim.x % 8 == 0) + row-major tile order:
  // each XCD gets a contiguous run of tiles; consecutive tiles share the
  // 128KB A-panel -> it stays in that XCD's private L2.
  const int nTN = N >> 7;
  const int q8 = gridDim.x >> 3;
  const int lin = (blockIdx.x & 7) * q8 + (blockIdx.x >> 3);
  const int tm = lin / nTN;
  const int tn = lin - tm * nTN;
  const long rowBase = (long)tm * 128;
  const long colBase = (long)tn * 128;

  const unsigned short* a0 = A + (size_t)rowBase * 512;
  const unsigned short* b0 = BT + (size_t)colBase * 512;

  floatx4 acc[4][4];
#pragma unroll
  for (int i = 0; i < 4; ++i)
#pragma unroll
    for (int j = 0; j < 4; ++j) acc[i][j] = (floatx4){0.f, 0.f, 0.f, 0.f};

  // 16B chunk c of a tile <-> LDS slot c (linear: gload_lds dest is
  // base + lane*16). Slot c=(row=c>>2, kcs=c&3) holds GLOBAL chunk
  // (row, kcs ^ ((row>>1)&3)) -- the bank-decorrelating XOR swizzle is
  // applied on the global source address, LDS stays linear.
  const int c0 = t, c1 = t + 256;
  const size_t gOff0 =
      (size_t)(c0 >> 2) * 512 + (size_t)((c0 & 3) ^ ((c0 >> 3) & 3)) * 8;
  const size_t gOff1 =
      (size_t)(c1 >> 2) * 512 + (size_t)((c1 & 3) ^ ((c1 >> 3) & 3)) * 8;
  const int ldsByte0 = wave * 1024;         // chunks w*64 + lane
  const int ldsByte1 = 4096 + wave * 1024;  // chunks 256 + w*64 + lane

#define STAGE(buf, k0)                                                       \
  do {                                                                       \
    gload_lds16(a0 + gOff0 + (k0), (AS3 char*)&As[(buf)][0] + ldsByte0);     \
    gload_lds16(a0 + gOff1 + (k0), (AS3 char*)&As[(buf)][0] + ldsByte1);     \
    gload_lds16(b0 + gOff0 + (k0), (AS3 char*)&Bs[(buf)][0] + ldsByte0);     \
    gload_lds16(b0 + gOff1 + (k0), (AS3 char*)&Bs[(buf)][0] + ldsByte1);     \
  } while (0)

  const int am = lane & 15;
  const int q = lane >> 4;  // which 8-elem k-chunk of the 32-wide row

  // prologue: stage tiles 0 and 1; wait for tile 0 (8 issued -> keep 4)
  STAGE(0, 0);
  STAGE(1, 32);
  asm volatile("s_waitcnt vmcnt(4)" ::: "memory");
  __builtin_amdgcn_sched_barrier(0);
  __builtin_amdgcn_s_barrier();

#pragma unroll
  for (int kt = 0; kt < 16; ++kt) {
    if (kt + 2 < 16) STAGE((kt + 2) % 3, (kt + 2) * 32);  // into buf of kt-1

    const unsigned short* As_ = &As[kt % 3][0];
    const unsigned short* Bs_ = &Bs[kt % 3][0];
    short8 af[4], bf[4];
#pragma unroll
    for (int i = 0; i < 4; ++i) {
      const int row = wm * 64 + i * 16 + am;
      af[i] = *(const short8*)&As_[row * 32 + ((q ^ ((row >> 1) & 3)) << 3)];
    }
#pragma unroll
    for (int j = 0; j < 4; ++j) {
      const int row = wn * 64 + j * 16 + am;
      bf[j] = *(const short8*)&Bs_[row * 32 + ((q ^ ((row >> 1) & 3)) << 3)];
    }
#pragma unroll
    for (int i = 0; i < 4; ++i)
#pragma unroll
      for (int j = 0; j < 4; ++j)
        acc[i][j] = __builtin_amdgcn_mfma_f32_16x16x32_bf16(af[i], bf[j], acc[i][j], 0, 0, 0);

    if (kt == 15) break;
    // retire tile kt+1's 4 loads (tile kt+2's 4 may stay in flight)
    if (kt < 14) asm volatile("s_waitcnt vmcnt(4)" ::: "memory");
    else         asm volatile("s_waitcnt vmcnt(0)" ::: "memory");
    __builtin_amdgcn_sched_barrier(0);
    __builtin_amdgcn_s_barrier();
  }
#undef STAGE

  // epilogue: C/D layout col=lane&15, row=(lane>>4)*4+reg  [m89-verified]
  const int q4 = (lane >> 4) << 2;
#pragma unroll
  for (int i = 0; i < 4; ++i) {
#pragma unroll
    for (int j = 0; j < 4; ++j) {
      const long col = colBase + wn * 64 + j * 16 + am;
      const float badd = bias ? bias[col] : 0.f;
      const long rowa = rowBase + wm * 64 + i * 16 + q4;
#pragma unroll
      for (int r = 0; r < 4; ++r)
        C[(size_t)(rowa + r) * N + col] = f2bf(acc[i][j][r] + badd);
    }
  }
}

// ---------------------------------------------------------------------------
// Per-(b,h) attention. LDS stride 65 (65 % 32 == 1): lanes with distinct
// j/kk land in distinct banks -> conflict-free scalar reads.
// ---------------------------------------------------------------------------
__global__ __launch_bounds__(256) void attn_kernel(
    const unsigned short* __restrict__ qkv, unsigned short* __restrict__ o) {
  const int b = blockIdx.x, h = blockIdx.y;
  __shared__ float q[17][65], k[17][65], v[17][65];
  __shared__ float S[17][17];
  const int t = threadIdx.x;
  const unsigned short* base = qkv + (size_t)b * 17 * 1536 + h * 64;

  for (int idx = t; idx < 3 * 136; idx += 256) {  // 136 = 17 rows * 8 chunks
    const int m = idx / 136, rem = idx - m * 136;
    const int r = rem >> 3, e0 = (rem & 7) << 3;
    uint4 u = *(const uint4*)(base + (size_t)r * 1536 + m * 512 + e0);
    float f[8];
    unpack8(u, f);
    float(*dst)[65] = (m == 0) ? q : (m == 1) ? k : v;
#pragma unroll
    for (int e = 0; e < 8; ++e) dst[r][e0 + e] = f[e];
  }
  __syncthreads();

  for (int idx = t; idx < 289; idx += 256) {
    const int j = idx / 17, kk = idx - j * 17;
    float s = 0.f;
#pragma unroll 8
    for (int e = 0; e < 64; ++e) s += q[j][e] * k[kk][e];
    S[j][kk] = s * 0.125f;  // / sqrt(64)
  }
  __syncthreads();

  if (t < 17) {
    float m = -1e30f;
#pragma unroll
    for (int kk = 0; kk < 17; ++kk) m = fmaxf(m, S[t][kk]);
    float tmp[17], sum = 0.f;
#pragma unroll
    for (int kk = 0; kk < 17; ++kk) { tmp[kk] = __expf(S[t][kk] - m); sum += tmp[kk]; }
    const float inv = 1.f / sum;
#pragma unroll
    for (int kk = 0; kk < 17; ++kk) S[t][kk] = tmp[kk] * inv;
  }
  __syncthreads();

  unsigned short* ob = o + (size_t)b * 17 * 512 + h * 64;
  for (int idx = t; idx < 136; idx += 256) {
    const int j = idx >> 3, e0 = (idx & 7) << 3;
    float ov[8] = {0, 0, 0, 0, 0, 0, 0, 0};
#pragma unroll
    for (int kk = 0; kk < 17; ++kk) {
      const float a = S[j][kk];
#pragma unroll
      for (int e = 0; e < 8; ++e) ov[e] += a * v[kk][e0 + e];
    }
    *(uint4*)(ob + (size_t)j * 512 + e0) = pack8(ov);
  }
}

// ---------------------------------------------------------------------------
// X = LN1(src_f32 + att_bf16; g,beta f32) -> bf16. One wave per row.
// ---------------------------------------------------------------------------
__global__ __launch_bounds__(256) void ln_res_kernel(
    const float* __restrict__ a, const unsigned short* __restrict__ b,
    const float* __restrict__ g, const float* __restrict__ beta,
    unsigned short* __restrict__ out) {
  const long row = (long)blockIdx.x * 4 + (threadIdx.x >> 6);
  const int lane = threadIdx.x & 63;
  const int d0 = lane * 8;

  const float4 a0 = *(const float4*)(a + (size_t)row * 512 + d0);
  const float4 a1 = *(const float4*)(a + (size_t)row * 512 + d0 + 4);
  const float fa[8] = {a0.x, a0.y, a0.z, a0.w, a1.x, a1.y, a1.z, a1.w};
  float fb[8], vals[8];
  unpack8(*(const uint4*)(b + (size_t)row * 512 + d0), fb);
  float s = 0.f, s2 = 0.f;
#pragma unroll
  for (int i = 0; i < 8; ++i) {
    vals[i] = fa[i] + fb[i];
    s += vals[i];
    s2 += vals[i] * vals[i];
  }
  const float mean = wave_sum(s) * (1.f / 512.f);
  const float var = wave_sum(s2) * (1.f / 512.f) - mean * mean;
  const float rs = rsqrtf(var + 1e-5f);

  const float4 g0 = *(const float4*)(g + d0);
  const float4 g1 = *(const float4*)(g + d0 + 4);
  const float4 b0 = *(const float4*)(beta + d0);
  const float4 b1 = *(const float4*)(beta + d0 + 4);
  const float fg[8]  = {g0.x, g0.y, g0.z, g0.w, g1.x, g1.y, g1.z, g1.w};
  const float fbt[8] = {b0.x, b0.y, b0.z, b0.w, b1.x, b1.y, b1.z, b1.w};
  float y[8];
#pragma unroll
  for (int i = 0; i < 8; ++i) y[i] = (vals[i] - mean) * rs * fg[i] + fbt[i];
  *(uint4*)(out + (size_t)row * 512 + d0) = pack8(y);
}

// ---------------------------------------------------------------------------
// out_f32 = LN2(x + gcn + b_gcn); gcn = Adiag[j]*h0[row] + sum_nbr w*h1[b,k]
// ---------------------------------------------------------------------------
__global__ __launch_bounds__(256) void gcn_ln_kernel(
    const unsigned short* __restrict__ x, const unsigned short* __restrict__ h01,
    const float* __restrict__ Adiag, const int* __restrict__ cnt,
    const int* __restrict__ nbrk, const float* __restrict__ nbrw,
    const float* __restrict__ bgcn,
    const float* __restrict__ g, const float* __restrict__ beta,
    float* __restrict__ out) {
  const long row = (long)blockIdx.x * 4 + (threadIdx.x >> 6);
  const int lane = threadIdx.x & 63;
  const int b = (int)(row / 17);
  const int j = (int)(row - (long)b * 17);
  const int d0 = lane * 8;

  float accv[8];
  {
    const float w = Adiag[j];
    float f[8];
    unpack8(*(const uint4*)(h01 + (size_t)row * 1024 + d0), f);
#pragma unroll
    for (int i = 0; i < 8; ++i) accv[i] = w * f[i];
  }
  const int c = cnt[j];
  for (int nb = 0; nb < c; ++nb) {
    const int kk = nbrk[j * 8 + nb];
    const float w = nbrw[j * 8 + nb];
    float f[8];
    unpack8(*(const uint4*)(h01 + ((size_t)b * 17 + kk) * 1024 + 512 + d0), f);
#pragma unroll
    for (int i = 0; i < 8; ++i) accv[i] += w * f[i];
  }

  float fx[8], vals[8];
  unpack8(*(const uint4*)(x + (size_t)row * 512 + d0), fx);
  const float4 bg0 = *(const float4*)(bgcn + d0);
  const float4 bg1 = *(const float4*)(bgcn + d0 + 4);
  const float fbg[8] = {bg0.x, bg0.y, bg0.z, bg0.w, bg1.x, bg1.y, bg1.z, bg1.w};
  float s = 0.f, s2 = 0.f;
#pragma unroll
  for (int i = 0; i < 8; ++i) {
    vals[i] = fx[i] + accv[i] + fbg[i];
    s += vals[i];
    s2 += vals[i] * vals[i];
  }
  const float mean = wave_sum(s) * (1.f / 512.f);
  const float var = wave_sum(s2) * (1.f / 512.f) - mean * mean;
  const float rs = rsqrtf(var + 1e-5f);

  const float4 g0 = *(const float4*)(g + d0);
  const float4 g1 = *(const float4*)(g + d0 + 4);
  const float4 bb0 = *(const float4*)(beta + d0);
  const float4 bb1 = *(const float4*)(beta + d0 + 4);
  const float fg[8]  = {g0.x, g0.y, g0.z, g0.w, g1.x, g1.y, g1.z, g1.w};
  const float fbt[8] = {bb0.x, bb0.y, bb0.z, bb0.w, bb1.x, bb1.y, bb1.z, bb1.w};
  float4 y0, y1;
  y0.x = (vals[0] - mean) * rs * fg[0] + fbt[0];
  y0.y = (vals[1] - mean) * rs * fg[1] + fbt[1];
  y0.z = (vals[2] - mean) * rs * fg[2] + fbt[2];
  y0.w = (vals[3] - mean) * rs * fg[3] + fbt[3];
  y1.x = (vals[4] - mean) * rs * fg[4] + fbt[4];
  y1.y = (vals[5] - mean) * rs * fg[5] + fbt[5];
  y1.z = (vals[6] - mean) * rs * fg[6] + fbt[6];
  y1.w = (vals[7] - mean) * rs * fg[7] + fbt[7];
  *(float4*)(out + (size_t)row * 512 + d0) = y0;
  *(float4*)(out + (size_t)row * 512 + d0 + 4) = y1;
}

// ---------------------------------------------------------------------------
// Weight transposes (f32 in) into [N][K] bf16 layouts
// ---------------------------------------------------------------------------
__global__ __launch_bounds__(256) void prep_transpose(
    const float* __restrict__ Wq, const float* __restrict__ Wk,
    const float* __restrict__ Wv, const float* __restrict__ Wo,
    const float* __restrict__ Wg,
    unsigned short* __restrict__ WT1, unsigned short* __restrict__ WT2,
    unsigned short* __restrict__ WT3) {
  const int idx = blockIdx.x * 256 + threadIdx.x;
  if (idx < 786432) {  // WT1[n][k]: n = which*512 + h*64 + e
    const int n = idx >> 9, k = idx & 511;
    const int which = n >> 9, nn = n & 511;
    const int hh = nn >> 6, e = nn & 63;
    const float* W = (which == 0) ? Wq : (which == 1) ? Wk : Wv;
    WT1[idx] = f2bf(W[hh * 32768 + k * 64 + e]);
  } else if (idx < 786432 + 262144) {  // WT2[n][k] = Wo[k][n]
    const int i2 = idx - 786432;
    const int n = i2 >> 9, k = i2 & 511;
    WT2[i2] = f2bf(Wo[k * 512 + n]);
  } else {  // WT3[n'][k] = Wg[which][k][n]
    const int i3 = idx - 1048576;
    const int n = i3 >> 9, k = i3 & 511;
    const int which = n >> 9, nn = n & 511;
    WT3[i3] = f2bf(Wg[which * 262144 + k * 512 + nn]);
  }
}

// ---------------------------------------------------------------------------
// bias concat (f32) + adjacency row-softmax + neighbor lists
// ---------------------------------------------------------------------------
__global__ __launch_bounds__(256) void prep_small(
    const float* __restrict__ bq, const float* __restrict__ bk,
    const float* __restrict__ bv, const float* __restrict__ bo,
    const float* __restrict__ e, const int* __restrict__ rows,
    const int* __restrict__ cols, int nnz,
    float* __restrict__ bias1, float* __restrict__ bias2,
    float* __restrict__ Adiag, int* __restrict__ cnt,
    int* __restrict__ nbrk, float* __restrict__ nbrw) {
  const int t = threadIdx.x;
  for (int i = t; i < 1536; i += 256)
    bias1[i] = (i < 512) ? bq[i] : (i < 1024) ? bk[i - 512] : bv[i - 1024];
  for (int i = t; i < 512; i += 256) bias2[i] = bo[i];
  if (t < 17) {
    float m = -1e30f;
    for (int i = 0; i < nnz; ++i)
      if (rows[i] == t) m = fmaxf(m, e[i]);
    float s = 0.f;
    for (int i = 0; i < nnz; ++i)
      if (rows[i] == t) s += __expf(e[i] - m);
    const float inv = 1.f / s;
    int c = 0;
    for (int i = 0; i < nnz; ++i)
      if (rows[i] == t) {
        const float w = __expf(e[i] - m) * inv;
        const int kk = cols[i];
        if (kk == t) Adiag[t] = w;
        else { nbrk[t * 8 + c] = kk; nbrw[t * 8 + c] = w; ++c; }
      }
    cnt[t] = c;
  }
}

// ---------------------------------------------------------------------------
extern "C" void kernel_launch(void* const* d_in, const int* in_sizes, int n_in,
                              void* d_out, int out_size, void* d_ws, size_t ws_size,
                              hipStream_t stream) {
  const float* src = (const float*)d_in[0];
  const float* Wq  = (const float*)d_in[1];
  const float* bq  = (const float*)d_in[2];
  const float* Wk  = (const float*)d_in[3];
  const float* bk  = (const float*)d_in[4];
  const float* Wv  = (const float*)d_in[5];
  const float* bv  = (const float*)d_in[6];
  const float* Wo  = (const float*)d_in[7];
  const float* bo  = (const float*)d_in[8];
  const float* ln1g = (const float*)d_in[9];
  const float* ln1b = (const float*)d_in[10];
  const float* Wg  = (const float*)d_in[11];
  const float* eg  = (const float*)d_in[12];
  const float* bg  = (const float*)d_in[13];
  const float* ln2g = (const float*)d_in[14];
  const float* ln2b = (const float*)d_in[15];
  const int* mrows = (const int*)d_in[16];
  const int* mcols = (const int*)d_in[17];
  const int nnz = in_sizes[16];

  float* out = (float*)d_out;
  char* ws = (char*)d_ws;

  unsigned short* WT1 = (unsigned short*)(ws + 0x0000000);
  unsigned short* WT2 = (unsigned short*)(ws + 0x0180000);
  unsigned short* WT3 = (unsigned short*)(ws + 0x0200000);
  float* bias1 = (float*)(ws + 0x0300000);
  float* bias2 = (float*)(ws + 0x0302000);
  float* Adiag = (float*)(ws + 0x0303000);
  int* cnt     = (int*)(ws + 0x0303100);
  int* nbrk    = (int*)(ws + 0x0303200);
  float* nbrw  = (float*)(ws + 0x0303600);
  unsigned short* SRCB = (unsigned short*)(ws + 0x0400000);
  unsigned short* QKV  = (unsigned short*)(ws + 0x4800000);
  unsigned short* O    = (unsigned short*)(ws + 0x0400000);  // after SRCB dead
  unsigned short* ATT  = (unsigned short*)(ws + 0x4800000);  // after QKV dead
  unsigned short* X    = (unsigned short*)(ws + 0x8C00000);
  unsigned short* H01  = (unsigned short*)(ws + 0x0400000);  // after O/ATT dead

  (void)n_in; (void)out_size; (void)ws_size;

  convert_src<<<17408, 256, 0, stream>>>(src, SRCB);
  prep_transpose<<<6144, 256, 0, stream>>>(Wq, Wk, Wv, Wo, Wg, WT1, WT2, WT3);
  prep_small<<<1, 256, 0, stream>>>(bq, bk, bv, bo, eg, mrows, mcols, nnz,
                                    bias1, bias2, Adiag, cnt, nbrk, nbrw);
  // 1-D grids: (M/128)*(N/128) = 544*{12,4,8}, all divisible by 8.
  gemm_bt<<<6528, 256, 0, stream>>>(SRCB, WT1, bias1, QKV, 1536);
  attn_kernel<<<dim3(4096, 8), 256, 0, stream>>>(QKV, O);
  gemm_bt<<<2176, 256, 0, stream>>>(O, WT2, bias2, ATT, 512);
  ln_res_kernel<<<17408, 256, 0, stream>>>(src, ATT, ln1g, ln1b, X);
  gemm_bt<<<4352, 256, 0, stream>>>(X, WT3, nullptr, H01, 1024);
  gcn_ln_kernel<<<17408, 256, 0, stream>>>(X, H01, Adiag, cnt, nbrk, nbrw, bg,
                                           ln2g, ln2b, out);
}

// Round 2
// 809.713 us; speedup vs baseline: 1.1579x; 1.1195x over previous
//
#include <hip/hip_runtime.h>

// ---------------------------------------------------------------------------
// ModifiedTransformerEncoderLayer on MI355X (gfx950)
// B=4096 J=17 D=512 H=8 DK=64, M=B*J=69632. I/O f32; compute bf16 MFMA.
//
// Round 6 (this round): attn_kernel rewritten as MFMA attention.
//  - one wave per (b,h); 4 waves/block, no cross-wave sync.
//  - S^T = K.Q^T via 2x2 tiles of mfma_f32_16x16x32_bf16 (row 16 padded by
//    clamping); Q/K fragments loaded DIRECTLY from global (dwordx4, the
//    verified A/B fragment layout: row=lane&15, k-off=8*(lane>>4)).
//  - softmax over kk is in-register: per-lane 4 regs + kk=16, reduced with
//    2 shfl_xor (16,32) across the 4 lane-groups holding a column.
//  - P repacked to K=32 A-fragment via 4 __shfl + bf16 packs; PV is one
//    mfma per (j-tile, e-tile) with V staged in LDS stride-76 (bank-clean).
//  Replaces ~300KB/block of scalar LDS reads (2 ds_read per FMA, MfmaUtil=0,
//  1.9e7 conflict cycles) with 16 MFMAs + ~12KB LDS traffic per wave.
//
// Round 5: gemm_bt triple-buffered LDS + counted vmcnt(4) + raw s_barrier;
// XCD-aware bijective block swizzle; 16B-chunk XOR LDS swizzle via
// inverse-swizzled global source addresses.
//
// ws layout (peak 0x11400000 = 276.1 MiB):
//   WT1 @0x000000  WT2 @0x180000  WT3 @0x200000  smalls @0x300000
//   SRCB @0x0400000 ; QKV @0x4800000 ; O @0x0400000 (SRCB dead)
//   ATT @0x4800000 (QKV dead) ; X @0x8C00000 ; H01 @0x0400000 (O/ATT dead)
// ---------------------------------------------------------------------------

typedef __attribute__((ext_vector_type(4))) float floatx4;
typedef __attribute__((ext_vector_type(8))) short short8;

#define AS1 __attribute__((address_space(1)))
#define AS3 __attribute__((address_space(3)))

__device__ __forceinline__ float bf2f(unsigned short u) {
  union { unsigned int i; float f; } x;
  x.i = ((unsigned int)u) << 16;
  return x.f;
}

__device__ __forceinline__ unsigned short f2bf(float f) {
  union { float f; unsigned int i; } x;
  x.f = f;
  unsigned int r = x.i + 0x7fffu + ((x.i >> 16) & 1u);  // RNE
  return (unsigned short)(r >> 16);
}

__device__ __forceinline__ void unpack8(uint4 u, float* f) {
  unsigned int uu[4] = {u.x, u.y, u.z, u.w};
#pragma unroll
  for (int i = 0; i < 4; ++i) {
    f[2 * i]     = bf2f((unsigned short)(uu[i] & 0xffffu));
    f[2 * i + 1] = bf2f((unsigned short)(uu[i] >> 16));
  }
}

__device__ __forceinline__ uint4 pack8(const float* f) {
  unsigned int uu[4];
#pragma unroll
  for (int i = 0; i < 4; ++i)
    uu[i] = (unsigned int)f2bf(f[2 * i]) | ((unsigned int)f2bf(f[2 * i + 1]) << 16);
  uint4 u; u.x = uu[0]; u.y = uu[1]; u.z = uu[2]; u.w = uu[3];
  return u;
}

__device__ __forceinline__ float wave_sum(float v) {
#pragma unroll
  for (int m = 1; m < 64; m <<= 1) v += __shfl_xor(v, m, 64);
  return v;
}

// async global->LDS, 16B/lane; LDS dest = wave-uniform base + lane*16
__device__ __forceinline__ void gload_lds16(const unsigned short* g, AS3 char* l) {
  __builtin_amdgcn_global_load_lds((const AS1 void*)g, (AS3 void*)l, 16, 0, 0);
}

// ---------------------------------------------------------------------------
// src f32 -> bf16, 8 elems/thread
// ---------------------------------------------------------------------------
__global__ __launch_bounds__(256) void convert_src(
    const float* __restrict__ in, unsigned short* __restrict__ out) {
  const size_t i = ((size_t)blockIdx.x * 256 + threadIdx.x) * 8;
  const float4 a = *(const float4*)(in + i);
  const float4 b = *(const float4*)(in + i + 4);
  const float f[8] = {a.x, a.y, a.z, a.w, b.x, b.y, b.z, b.w};
  *(uint4*)(out + i) = pack8(f);
}

// ---------------------------------------------------------------------------
// GEMM: C[M,N] = A[M,512] @ BT[N,512]^T (+ bias[N]), bf16 in/out, f32 accum.
// 128x128 tile, BK=32, 4 waves of 4x4 16x16x32 MFMA.
// Triple-buffered async LDS staging, counted vmcnt, raw s_barrier.
// Launch with 1-D grid = (M/128)*(N/128), divisible by 8.
// ---------------------------------------------------------------------------
__global__ __launch_bounds__(256) void gemm_bt(
    const unsigned short* __restrict__ A,
    const unsigned short* __restrict__ BT,
    const float* __restrict__ bias,
    unsigned short* __restrict__ C, int N) {
  __shared__ unsigned short As[3][128 * 32];
  __shared__ unsigned short Bs[3][128 * 32];
  const int t = threadIdx.x;
  const int wave = t >> 6;
  const int lane = t & 63;
  const int wm = wave >> 1, wn = wave & 1;

  // XCD-aware bijective swizzle (gridDim.x % 8 == 0) + row-major tile order.
  const int nTN = N >> 7;
  const int q8 = gridDim.x >> 3;
  const int lin = (blockIdx.x & 7) * q8 + (blockIdx.x >> 3);
  const int tm = lin / nTN;
  const int tn = lin - tm * nTN;
  const long rowBase = (long)tm * 128;
  const long colBase = (long)tn * 128;

  const unsigned short* a0 = A + (size_t)rowBase * 512;
  const unsigned short* b0 = BT + (size_t)colBase * 512;

  floatx4 acc[4][4];
#pragma unroll
  for (int i = 0; i < 4; ++i)
#pragma unroll
    for (int j = 0; j < 4; ++j) acc[i][j] = (floatx4){0.f, 0.f, 0.f, 0.f};

  // LDS slot c=(row=c>>2, kcs=c&3) holds GLOBAL chunk (row, kcs ^ ((row>>1)&3))
  const int c0 = t, c1 = t + 256;
  const size_t gOff0 =
      (size_t)(c0 >> 2) * 512 + (size_t)((c0 & 3) ^ ((c0 >> 3) & 3)) * 8;
  const size_t gOff1 =
      (size_t)(c1 >> 2) * 512 + (size_t)((c1 & 3) ^ ((c1 >> 3) & 3)) * 8;
  const int ldsByte0 = wave * 1024;
  const int ldsByte1 = 4096 + wave * 1024;

#define STAGE(buf, k0)                                                       \
  do {                                                                       \
    gload_lds16(a0 + gOff0 + (k0), (AS3 char*)&As[(buf)][0] + ldsByte0);     \
    gload_lds16(a0 + gOff1 + (k0), (AS3 char*)&As[(buf)][0] + ldsByte1);     \
    gload_lds16(b0 + gOff0 + (k0), (AS3 char*)&Bs[(buf)][0] + ldsByte0);     \
    gload_lds16(b0 + gOff1 + (k0), (AS3 char*)&Bs[(buf)][0] + ldsByte1);     \
  } while (0)

  const int am = lane & 15;
  const int q = lane >> 4;

  STAGE(0, 0);
  STAGE(1, 32);
  asm volatile("s_waitcnt vmcnt(4)" ::: "memory");
  __builtin_amdgcn_sched_barrier(0);
  __builtin_amdgcn_s_barrier();

#pragma unroll
  for (int kt = 0; kt < 16; ++kt) {
    if (kt + 2 < 16) STAGE((kt + 2) % 3, (kt + 2) * 32);

    const unsigned short* As_ = &As[kt % 3][0];
    const unsigned short* Bs_ = &Bs[kt % 3][0];
    short8 af[4], bf[4];
#pragma unroll
    for (int i = 0; i < 4; ++i) {
      const int row = wm * 64 + i * 16 + am;
      af[i] = *(const short8*)&As_[row * 32 + ((q ^ ((row >> 1) & 3)) << 3)];
    }
#pragma unroll
    for (int j = 0; j < 4; ++j) {
      const int row = wn * 64 + j * 16 + am;
      bf[j] = *(const short8*)&Bs_[row * 32 + ((q ^ ((row >> 1) & 3)) << 3)];
    }
#pragma unroll
    for (int i = 0; i < 4; ++i)
#pragma unroll
      for (int j = 0; j < 4; ++j)
        acc[i][j] = __builtin_amdgcn_mfma_f32_16x16x32_bf16(af[i], bf[j], acc[i][j], 0, 0, 0);

    if (kt == 15) break;
    if (kt < 14) asm volatile("s_waitcnt vmcnt(4)" ::: "memory");
    else         asm volatile("s_waitcnt vmcnt(0)" ::: "memory");
    __builtin_amdgcn_sched_barrier(0);
    __builtin_amdgcn_s_barrier();
  }
#undef STAGE

  // epilogue: C/D layout col=lane&15, row=(lane>>4)*4+reg  [m89-verified]
  const int q4 = (lane >> 4) << 2;
#pragma unroll
  for (int i = 0; i < 4; ++i) {
#pragma unroll
    for (int j = 0; j < 4; ++j) {
      const long col = colBase + wn * 64 + j * 16 + am;
      const float badd = bias ? bias[col] : 0.f;
      const long rowa = rowBase + wm * 64 + i * 16 + q4;
#pragma unroll
      for (int r = 0; r < 4; ++r)
        C[(size_t)(rowa + r) * N + col] = f2bf(acc[i][j][r] + badd);
    }
  }
}

// ---------------------------------------------------------------------------
// MFMA attention: one wave per (b,h). grid = 8192 blocks x 256 thr (4 waves).
// S^T = K.Q^T (2x2 tiles of 16x16x32, row 16 clamped), in-register softmax,
// P repacked via shfl to the K=32 A-fragment, PV from LDS-staged V.
// ---------------------------------------------------------------------------
__global__ __launch_bounds__(256) void attn_kernel(
    const unsigned short* __restrict__ qkv, unsigned short* __restrict__ o) {
  __shared__ unsigned short Vl[4][17][76];  // stride 76: bank-clean frag reads
  const int t = threadIdx.x;
  const int wave = t >> 6, lane = t & 63;
  const int wid = blockIdx.x * 4 + wave;
  const int b = wid >> 3, h = wid & 7;
  const int e = lane & 15, g = lane >> 4;

  const unsigned short* base = qkv + (size_t)b * 17 * 1536 + h * 64;

  // ---- stage V rows 0..16 into LDS (row-major, stride 76 shorts) ----
  unsigned short (*V)[76] = Vl[wave];
  for (int c = lane; c < 136; c += 64) {  // 136 = 17 rows * 8 chunks
    const int kk = c >> 3, e0 = (c & 7) << 3;
    const uint4 u = *(const uint4*)(base + (size_t)kk * 1536 + 1024 + e0);
    *(uint2*)&V[kk][e0]     = make_uint2(u.x, u.y);
    *(uint2*)&V[kk][e0 + 4] = make_uint2(u.z, u.w);
  }

  // ---- Q/K fragments direct from global (row=lane&15, k-off=8*g) ----
  const int ko = g << 3;
  const unsigned short* qrow  = base + (size_t)e * 1536;
  const unsigned short* row16 = base + (size_t)16 * 1536;
  const short8 Q0  = *(const short8*)(qrow + ko);
  const short8 Q1  = *(const short8*)(qrow + 32 + ko);
  const short8 K0  = *(const short8*)(qrow + 512 + ko);
  const short8 K1  = *(const short8*)(qrow + 512 + 32 + ko);
  const short8 Qb0 = *(const short8*)(row16 + ko);
  const short8 Qb1 = *(const short8*)(row16 + 32 + ko);
  const short8 Kb0 = *(const short8*)(row16 + 512 + ko);
  const short8 Kb1 = *(const short8*)(row16 + 512 + 32 + ko);

  // ---- S^T tiles: sT[mi][ni], mi = kk-tile (A=K), ni = j-tile (B=Q) ----
  floatx4 sT[2][2];
#pragma unroll
  for (int i = 0; i < 2; ++i)
#pragma unroll
    for (int j = 0; j < 2; ++j) sT[i][j] = (floatx4){0.f, 0.f, 0.f, 0.f};
  sT[0][0] = __builtin_amdgcn_mfma_f32_16x16x32_bf16(K0, Q0, sT[0][0], 0, 0, 0);
  sT[0][0] = __builtin_amdgcn_mfma_f32_16x16x32_bf16(K1, Q1, sT[0][0], 0, 0, 0);
  sT[0][1] = __builtin_amdgcn_mfma_f32_16x16x32_bf16(K0, Qb0, sT[0][1], 0, 0, 0);
  sT[0][1] = __builtin_amdgcn_mfma_f32_16x16x32_bf16(K1, Qb1, sT[0][1], 0, 0, 0);
  sT[1][0] = __builtin_amdgcn_mfma_f32_16x16x32_bf16(Kb0, Q0, sT[1][0], 0, 0, 0);
  sT[1][0] = __builtin_amdgcn_mfma_f32_16x16x32_bf16(Kb1, Q1, sT[1][0], 0, 0, 0);
  sT[1][1] = __builtin_amdgcn_mfma_f32_16x16x32_bf16(Kb0, Qb0, sT[1][1], 0, 0, 0);
  sT[1][1] = __builtin_amdgcn_mfma_f32_16x16x32_bf16(Kb1, Qb1, sT[1][1], 0, 0, 0);

  // ---- softmax over kk (lane holds kk=4g+r of column j=e; kk=16 in sT[1]) ----
  // then repack P into K=32 A-fragments PA[jt] via shfl.
  short8 PA[2];
#pragma unroll
  for (int ni = 0; ni < 2; ++ni) {
    float v[4];
#pragma unroll
    for (int r = 0; r < 4; ++r) v[r] = sT[0][ni][r] * 0.125f;
    const float v16 = sT[1][ni][0] * 0.125f;
    float m = fmaxf(fmaxf(v[0], v[1]), fmaxf(v[2], v[3]));
    if (g == 0) m = fmaxf(m, v16);
    m = fmaxf(m, __shfl_xor(m, 16, 64));
    m = fmaxf(m, __shfl_xor(m, 32, 64));
    float p[4], sum = 0.f;
#pragma unroll
    for (int r = 0; r < 4; ++r) { p[r] = __expf(v[r] - m); sum += p[r]; }
    float p16 = (g == 0) ? __expf(v16 - m) : 0.f;
    sum += p16;
    sum += __shfl_xor(sum, 16, 64);
    sum += __shfl_xor(sum, 32, 64);
    const float inv = 1.f / sum;
#pragma unroll
    for (int r = 0; r < 4; ++r) p[r] *= inv;
    p16 *= inv;

    const unsigned int lo = (unsigned int)f2bf(p[0]) | ((unsigned int)f2bf(p[1]) << 16);
    const unsigned int hi = (unsigned int)f2bf(p[2]) | ((unsigned int)f2bf(p[3]) << 16);
    const unsigned int w16 = (unsigned int)f2bf(p16);

    // target lane (g, jj=lane&15) needs column (ni?16:jj)'s kk = 8g..8g+7
    const int colsrc = ni ? 0 : e;
    const int s0 = colsrc + ((g & 1) << 5);
    unsigned int w0 = __shfl(lo, s0, 64);
    unsigned int w1 = __shfl(hi, s0, 64);
    unsigned int w2 = __shfl(lo, s0 + 16, 64);
    unsigned int w3 = __shfl(hi, s0 + 16, 64);
    const unsigned int a16 = __shfl(w16, colsrc, 64);
    if (g == 2) { w0 = a16; w1 = 0; w2 = 0; w3 = 0; }
    if (g == 3) { w0 = 0; w1 = 0; w2 = 0; w3 = 0; }
    union { unsigned int u[4]; short8 s; } fa;
    fa.u[0] = w0; fa.u[1] = w1; fa.u[2] = w2; fa.u[3] = w3;
    PA[ni] = fa.s;
  }

  // ---- PV: O tiles o0 (j=0..15), o1 (j=16) per e'-tile t ----
  floatx4 o0[4], o1[4];
#pragma unroll
  for (int tt = 0; tt < 4; ++tt) {
    o0[tt] = (floatx4){0.f, 0.f, 0.f, 0.f};
    o1[tt] = (floatx4){0.f, 0.f, 0.f, 0.f};
  }
#pragma unroll
  for (int tt = 0; tt < 4; ++tt) {
    const int c = tt * 16 + e;
    union { unsigned int u[4]; short8 s; } fb;
#pragma unroll
    for (int i = 0; i < 4; ++i) {
      int ka = (g << 3) + 2 * i;     // kk for element 2i
      int kb = ka + 1;
      if (ka > 16) ka = 16;
      if (kb > 16) kb = 16;
      fb.u[i] = (unsigned int)V[ka][c] | ((unsigned int)V[kb][c] << 16);
    }
    o0[tt] = __builtin_amdgcn_mfma_f32_16x16x32_bf16(PA[0], fb.s, o0[tt], 0, 0, 0);
    o1[tt] = __builtin_amdgcn_mfma_f32_16x16x32_bf16(PA[1], fb.s, o1[tt], 0, 0, 0);
  }

  // ---- store: C layout col=lane&15 (+16t), row=4g+r (+16 for o1) ----
  unsigned short* ob = o + (size_t)b * 17 * 512 + h * 64;
#pragma unroll
  for (int tt = 0; tt < 4; ++tt)
#pragma unroll
    for (int r = 0; r < 4; ++r)
      ob[(size_t)(4 * g + r) * 512 + tt * 16 + e] = f2bf(o0[tt][r]);
  if (g == 0) {
#pragma unroll
    for (int tt = 0; tt < 4; ++tt)
      ob[(size_t)16 * 512 + tt * 16 + e] = f2bf(o1[tt][0]);
  }
}

// ---------------------------------------------------------------------------
// X = LN1(src_f32 + att_bf16; g,beta f32) -> bf16. One wave per row.
// ---------------------------------------------------------------------------
__global__ __launch_bounds__(256) void ln_res_kernel(
    const float* __restrict__ a, const unsigned short* __restrict__ b,
    const float* __restrict__ g, const float* __restrict__ beta,
    unsigned short* __restrict__ out) {
  const long row = (long)blockIdx.x * 4 + (threadIdx.x >> 6);
  const int lane = threadIdx.x & 63;
  const int d0 = lane * 8;

  const float4 a0 = *(const float4*)(a + (size_t)row * 512 + d0);
  const float4 a1 = *(const float4*)(a + (size_t)row * 512 + d0 + 4);
  const float fa[8] = {a0.x, a0.y, a0.z, a0.w, a1.x, a1.y, a1.z, a1.w};
  float fb[8], vals[8];
  unpack8(*(const uint4*)(b + (size_t)row * 512 + d0), fb);
  float s = 0.f, s2 = 0.f;
#pragma unroll
  for (int i = 0; i < 8; ++i) {
    vals[i] = fa[i] + fb[i];
    s += vals[i];
    s2 += vals[i] * vals[i];
  }
  const float mean = wave_sum(s) * (1.f / 512.f);
  const float var = wave_sum(s2) * (1.f / 512.f) - mean * mean;
  const float rs = rsqrtf(var + 1e-5f);

  const float4 g0 = *(const float4*)(g + d0);
  const float4 g1 = *(const float4*)(g + d0 + 4);
  const float4 b0 = *(const float4*)(beta + d0);
  const float4 b1 = *(const float4*)(beta + d0 + 4);
  const float fg[8]  = {g0.x, g0.y, g0.z, g0.w, g1.x, g1.y, g1.z, g1.w};
  const float fbt[8] = {b0.x, b0.y, b0.z, b0.w, b1.x, b1.y, b1.z, b1.w};
  float y[8];
#pragma unroll
  for (int i = 0; i < 8; ++i) y[i] = (vals[i] - mean) * rs * fg[i] + fbt[i];
  *(uint4*)(out + (size_t)row * 512 + d0) = pack8(y);
}

// ---------------------------------------------------------------------------
// out_f32 = LN2(x + gcn + b_gcn); gcn = Adiag[j]*h0[row] + sum_nbr w*h1[b,k]
// ---------------------------------------------------------------------------
__global__ __launch_bounds__(256) void gcn_ln_kernel(
    const unsigned short* __restrict__ x, const unsigned short* __restrict__ h01,
    const float* __restrict__ Adiag, const int* __restrict__ cnt,
    const int* __restrict__ nbrk, const float* __restrict__ nbrw,
    const float* __restrict__ bgcn,
    const float* __restrict__ g, const float* __restrict__ beta,
    float* __restrict__ out) {
  const long row = (long)blockIdx.x * 4 + (threadIdx.x >> 6);
  const int lane = threadIdx.x & 63;
  const int b = (int)(row / 17);
  const int j = (int)(row - (long)b * 17);
  const int d0 = lane * 8;

  float accv[8];
  {
    const float w = Adiag[j];
    float f[8];
    unpack8(*(const uint4*)(h01 + (size_t)row * 1024 + d0), f);
#pragma unroll
    for (int i = 0; i < 8; ++i) accv[i] = w * f[i];
  }
  const int c = cnt[j];
  for (int nb = 0; nb < c; ++nb) {
    const int kk = nbrk[j * 8 + nb];
    const float w = nbrw[j * 8 + nb];
    float f[8];
    unpack8(*(const uint4*)(h01 + ((size_t)b * 17 + kk) * 1024 + 512 + d0), f);
#pragma unroll
    for (int i = 0; i < 8; ++i) accv[i] += w * f[i];
  }

  float fx[8], vals[8];
  unpack8(*(const uint4*)(x + (size_t)row * 512 + d0), fx);
  const float4 bg0 = *(const float4*)(bgcn + d0);
  const float4 bg1 = *(const float4*)(bgcn + d0 + 4);
  const float fbg[8] = {bg0.x, bg0.y, bg0.z, bg0.w, bg1.x, bg1.y, bg1.z, bg1.w};
  float s = 0.f, s2 = 0.f;
#pragma unroll
  for (int i = 0; i < 8; ++i) {
    vals[i] = fx[i] + accv[i] + fbg[i];
    s += vals[i];
    s2 += vals[i] * vals[i];
  }
  const float mean = wave_sum(s) * (1.f / 512.f);
  const float var = wave_sum(s2) * (1.f / 512.f) - mean * mean;
  const float rs = rsqrtf(var + 1e-5f);

  const float4 g0 = *(const float4*)(g + d0);
  const float4 g1 = *(const float4*)(g + d0 + 4);
  const float4 bb0 = *(const float4*)(beta + d0);
  const float4 bb1 = *(const float4*)(beta + d0 + 4);
  const float fg[8]  = {g0.x, g0.y, g0.z, g0.w, g1.x, g1.y, g1.z, g1.w};
  const float fbt[8] = {bb0.x, bb0.y, bb0.z, bb0.w, bb1.x, bb1.y, bb1.z, bb1.w};
  float4 y0, y1;
  y0.x = (vals[0] - mean) * rs * fg[0] + fbt[0];
  y0.y = (vals[1] - mean) * rs * fg[1] + fbt[1];
  y0.z = (vals[2] - mean) * rs * fg[2] + fbt[2];
  y0.w = (vals[3] - mean) * rs * fg[3] + fbt[3];
  y1.x = (vals[4] - mean) * rs * fg[4] + fbt[4];
  y1.y = (vals[5] - mean) * rs * fg[5] + fbt[5];
  y1.z = (vals[6] - mean) * rs * fg[6] + fbt[6];
  y1.w = (vals[7] - mean) * rs * fg[7] + fbt[7];
  *(float4*)(out + (size_t)row * 512 + d0) = y0;
  *(float4*)(out + (size_t)row * 512 + d0 + 4) = y1;
}

// ---------------------------------------------------------------------------
// Weight transposes (f32 in) into [N][K] bf16 layouts
// ---------------------------------------------------------------------------
__global__ __launch_bounds__(256) void prep_transpose(
    const float* __restrict__ Wq, const float* __restrict__ Wk,
    const float* __restrict__ Wv, const float* __restrict__ Wo,
    const float* __restrict__ Wg,
    unsigned short* __restrict__ WT1, unsigned short* __restrict__ WT2,
    unsigned short* __restrict__ WT3) {
  const int idx = blockIdx.x * 256 + threadIdx.x;
  if (idx < 786432) {  // WT1[n][k]: n = which*512 + h*64 + e
    const int n = idx >> 9, k = idx & 511;
    const int which = n >> 9, nn = n & 511;
    const int hh = nn >> 6, e = nn & 63;
    const float* W = (which == 0) ? Wq : (which == 1) ? Wk : Wv;
    WT1[idx] = f2bf(W[hh * 32768 + k * 64 + e]);
  } else if (idx < 786432 + 262144) {  // WT2[n][k] = Wo[k][n]
    const int i2 = idx - 786432;
    const int n = i2 >> 9, k = i2 & 511;
    WT2[i2] = f2bf(Wo[k * 512 + n]);
  } else {  // WT3[n'][k] = Wg[which][k][n]
    const int i3 = idx - 1048576;
    const int n = i3 >> 9, k = i3 & 511;
    const int which = n >> 9, nn = n & 511;
    WT3[i3] = f2bf(Wg[which * 262144 + k * 512 + nn]);
  }
}

// ---------------------------------------------------------------------------
// bias concat (f32) + adjacency row-softmax + neighbor lists
// ---------------------------------------------------------------------------
__global__ __launch_bounds__(256) void prep_small(
    const float* __restrict__ bq, const float* __restrict__ bk,
    const float* __restrict__ bv, const float* __restrict__ bo,
    const float* __restrict__ e, const int* __restrict__ rows,
    const int* __restrict__ cols, int nnz,
    float* __restrict__ bias1, float* __restrict__ bias2,
    float* __restrict__ Adiag, int* __restrict__ cnt,
    int* __restrict__ nbrk, float* __restrict__ nbrw) {
  const int t = threadIdx.x;
  for (int i = t; i < 1536; i += 256)
    bias1[i] = (i < 512) ? bq[i] : (i < 1024) ? bk[i - 512] : bv[i - 1024];
  for (int i = t; i < 512; i += 256) bias2[i] = bo[i];
  if (t < 17) {
    float m = -1e30f;
    for (int i = 0; i < nnz; ++i)
      if (rows[i] == t) m = fmaxf(m, e[i]);
    float s = 0.f;
    for (int i = 0; i < nnz; ++i)
      if (rows[i] == t) s += __expf(e[i] - m);
    const float inv = 1.f / s;
    int c = 0;
    for (int i = 0; i < nnz; ++i)
      if (rows[i] == t) {
        const float w = __expf(e[i] - m) * inv;
        const int kk = cols[i];
        if (kk == t) Adiag[t] = w;
        else { nbrk[t * 8 + c] = kk; nbrw[t * 8 + c] = w; ++c; }
      }
    cnt[t] = c;
  }
}

// ---------------------------------------------------------------------------
extern "C" void kernel_launch(void* const* d_in, const int* in_sizes, int n_in,
                              void* d_out, int out_size, void* d_ws, size_t ws_size,
                              hipStream_t stream) {
  const float* src = (const float*)d_in[0];
  const float* Wq  = (const float*)d_in[1];
  const float* bq  = (const float*)d_in[2];
  const float* Wk  = (const float*)d_in[3];
  const float* bk  = (const float*)d_in[4];
  const float* Wv  = (const float*)d_in[5];
  const float* bv  = (const float*)d_in[6];
  const float* Wo  = (const float*)d_in[7];
  const float* bo  = (const float*)d_in[8];
  const float* ln1g = (const float*)d_in[9];
  const float* ln1b = (const float*)d_in[10];
  const float* Wg  = (const float*)d_in[11];
  const float* eg  = (const float*)d_in[12];
  const float* bg  = (const float*)d_in[13];
  const float* ln2g = (const float*)d_in[14];
  const float* ln2b = (const float*)d_in[15];
  const int* mrows = (const int*)d_in[16];
  const int* mcols = (const int*)d_in[17];
  const int nnz = in_sizes[16];

  float* out = (float*)d_out;
  char* ws = (char*)d_ws;

  unsigned short* WT1 = (unsigned short*)(ws + 0x0000000);
  unsigned short* WT2 = (unsigned short*)(ws + 0x0180000);
  unsigned short* WT3 = (unsigned short*)(ws + 0x0200000);
  float* bias1 = (float*)(ws + 0x0300000);
  float* bias2 = (float*)(ws + 0x0302000);
  float* Adiag = (float*)(ws + 0x0303000);
  int* cnt     = (int*)(ws + 0x0303100);
  int* nbrk    = (int*)(ws + 0x0303200);
  float* nbrw  = (float*)(ws + 0x0303600);
  unsigned short* SRCB = (unsigned short*)(ws + 0x0400000);
  unsigned short* QKV  = (unsigned short*)(ws + 0x4800000);
  unsigned short* O    = (unsigned short*)(ws + 0x0400000);  // after SRCB dead
  unsigned short* ATT  = (unsigned short*)(ws + 0x4800000);  // after QKV dead
  unsigned short* X    = (unsigned short*)(ws + 0x8C00000);
  unsigned short* H01  = (unsigned short*)(ws + 0x0400000);  // after O/ATT dead

  (void)n_in; (void)out_size; (void)ws_size;

  convert_src<<<17408, 256, 0, stream>>>(src, SRCB);
  prep_transpose<<<6144, 256, 0, stream>>>(Wq, Wk, Wv, Wo, Wg, WT1, WT2, WT3);
  prep_small<<<1, 256, 0, stream>>>(bq, bk, bv, bo, eg, mrows, mcols, nnz,
                                    bias1, bias2, Adiag, cnt, nbrk, nbrw);
  // 1-D grids: (M/128)*(N/128) = 544*{12,4,8}, all divisible by 8.
  gemm_bt<<<6528, 256, 0, stream>>>(SRCB, WT1, bias1, QKV, 1536);
  attn_kernel<<<8192, 256, 0, stream>>>(QKV, O);
  gemm_bt<<<2176, 256, 0, stream>>>(O, WT2, bias2, ATT, 512);
  ln_res_kernel<<<17408, 256, 0, stream>>>(src, ATT, ln1g, ln1b, X);
  gemm_bt<<<4352, 256, 0, stream>>>(X, WT3, nullptr, H01, 1024);
  gcn_ln_kernel<<<17408, 256, 0, stream>>>(X, H01, Adiag, cnt, nbrk, nbrw, bg,
                                           ln2g, ln2b, out);
}

// Round 5
// 795.082 us; speedup vs baseline: 1.1793x; 1.0184x over previous
//
#include <hip/hip_runtime.h>

// ---------------------------------------------------------------------------
// ModifiedTransformerEncoderLayer on MI355X (gfx950)
// B=4096 J=17 D=512 H=8 DK=64, M=B*J=69632. I/O f32; compute bf16 MFMA.
//
// Round 9 (this round): final resubmit of the 8-phase 256x256 gemm_bt
// (rounds 7/8 died to container failure; offline audit found no fault:
// uniform barrier counts, satisfiable waitcnts, exact-fit LDS DMA bounds,
// race-free stage/read ledger). Hardenings vs round 8: explicit full
// vmcnt/lgkmcnt drain before the epilogue. If this fails again, revert to
// the round-5 triple-buffer 128^2 GEMM (known-good 809us config).
//
// Schedule (T2+T3+T4+T5): BK=64, 8 waves (2Mx4N), per-wave 128x64 output,
// 2-buffer 128KB LDS [buf][kh][256 rows][4x16B chunks], per-phase
// {ds_read frags | stage 1 half-tile | barrier | lgkmcnt(0) | setprio(1)
//  16 MFMA setprio(0) | counted vmcnt | barrier}. vmcnt(8) at ph1/ph3 only
// (tail: vmcnt(4)@kt6ph3, vmcnt(0)@kt7ph1). k-chunk XOR swizzle
// cc^((row>>1)&3) via inverse-swizzled global source (gload_lds dest linear)
// + swizzled ds_read -> 2-way max bank access.
// Stage ledger (K-tile kt): ph0:A(kt+1,k1) ph1:B(kt+1,k1) ph2:A(kt+2,k0)
// ph3:B(kt+2,k0). Prologue: A0k0,B0k0,A0k1,B0k1,A1k0,B1k0 then vmcnt(8).
//
// Round 6: attn_kernel = MFMA attention (S^T=K.Q^T, in-register softmax,
// shfl repack, PV from LDS V). Round 5: XCD swizzle (kept).
//
// ws layout (peak 0x11400000 = 276.1 MiB):
//   WT1 @0x000000  WT2 @0x180000  WT3 @0x200000  smalls @0x300000
//   SRCB @0x0400000 ; QKV @0x4800000 ; O @0x0400000 (SRCB dead)
//   ATT @0x4800000 (QKV dead) ; X @0x8C00000 ; H01 @0x0400000 (O/ATT dead)
// ---------------------------------------------------------------------------

typedef __attribute__((ext_vector_type(4))) float floatx4;
typedef __attribute__((ext_vector_type(8))) short short8;

#define AS1 __attribute__((address_space(1)))
#define AS3 __attribute__((address_space(3)))

__device__ __forceinline__ float bf2f(unsigned short u) {
  union { unsigned int i; float f; } x;
  x.i = ((unsigned int)u) << 16;
  return x.f;
}

__device__ __forceinline__ unsigned short f2bf(float f) {
  union { float f; unsigned int i; } x;
  x.f = f;
  unsigned int r = x.i + 0x7fffu + ((x.i >> 16) & 1u);  // RNE
  return (unsigned short)(r >> 16);
}

__device__ __forceinline__ void unpack8(uint4 u, float* f) {
  unsigned int uu[4] = {u.x, u.y, u.z, u.w};
#pragma unroll
  for (int i = 0; i < 4; ++i) {
    f[2 * i]     = bf2f((unsigned short)(uu[i] & 0xffffu));
    f[2 * i + 1] = bf2f((unsigned short)(uu[i] >> 16));
  }
}

__device__ __forceinline__ uint4 pack8(const float* f) {
  unsigned int uu[4];
#pragma unroll
  for (int i = 0; i < 4; ++i)
    uu[i] = (unsigned int)f2bf(f[2 * i]) | ((unsigned int)f2bf(f[2 * i + 1]) << 16);
  uint4 u; u.x = uu[0]; u.y = uu[1]; u.z = uu[2]; u.w = uu[3];
  return u;
}

__device__ __forceinline__ float wave_sum(float v) {
#pragma unroll
  for (int m = 1; m < 64; m <<= 1) v += __shfl_xor(v, m, 64);
  return v;
}

// async global->LDS, 16B/lane; LDS dest = wave-uniform base + lane*16
__device__ __forceinline__ void gload_lds16(const unsigned short* g, AS3 char* l) {
  __builtin_amdgcn_global_load_lds((const AS1 void*)g, (AS3 void*)l, 16, 0, 0);
}

// ---------------------------------------------------------------------------
// src f32 -> bf16, 8 elems/thread
// ---------------------------------------------------------------------------
__global__ __launch_bounds__(256) void convert_src(
    const float* __restrict__ in, unsigned short* __restrict__ out) {
  const size_t i = ((size_t)blockIdx.x * 256 + threadIdx.x) * 8;
  const float4 a = *(const float4*)(in + i);
  const float4 b = *(const float4*)(in + i + 4);
  const float f[8] = {a.x, a.y, a.z, a.w, b.x, b.y, b.z, b.w};
  *(uint4*)(out + i) = pack8(f);
}

// ---------------------------------------------------------------------------
// GEMM helpers: stage one half-tile (2 x 128 rows x 32 k-shorts)
// ---------------------------------------------------------------------------
__device__ __forceinline__ void stgA(const unsigned short* a0, size_t gTh,
                                     AS3 char* L, int ldsW, int bb, int kt,
                                     int kh) {
  gload_lds16(a0 + gTh + kt * 64 + kh * 32,
              L + bb * 32768 + kh * 16384 + ldsW);
  gload_lds16(a0 + gTh + 65536 + kt * 64 + kh * 32,
              L + bb * 32768 + kh * 16384 + 8192 + ldsW);
}
__device__ __forceinline__ void stgB(const unsigned short* b0, size_t gTh,
                                     AS3 char* L, int ldsW, int bb, int kt,
                                     int kh) {
  gload_lds16(b0 + gTh + kt * 64 + kh * 32,
              L + 65536 + bb * 32768 + kh * 16384 + ldsW);
  gload_lds16(b0 + gTh + 65536 + kt * 64 + kh * 32,
              L + 65536 + bb * 32768 + kh * 16384 + 8192 + ldsW);
}

// One K-tile (BK=64) = 4 phases. BB = LDS buffer parity (compile-time).
template <int BB>
__device__ __forceinline__ void kt_step(
    int kt, const char* Lr, AS3 char* L,
    const unsigned short* a0, const unsigned short* b0, size_t gTh, int ldsW,
    int aBase, int bBase, floatx4 (&acc)[8][4]) {
  constexpr int base = BB * 32768;
  short8 afL[4], afH[4], bf[4];

  // ---------------- ph0: acc[0..3][*] x k-half0 ----------------
#pragma unroll
  for (int i = 0; i < 4; ++i)
    afL[i] = *(const short8*)(Lr + base + aBase + i * 1024);
#pragma unroll
  for (int j = 0; j < 4; ++j)
    bf[j] = *(const short8*)(Lr + base + bBase + j * 1024);
  if (kt < 7) stgA(a0, gTh, L, ldsW, BB ^ 1, kt + 1, 1);
  __builtin_amdgcn_s_barrier();
  asm volatile("s_waitcnt lgkmcnt(0)" ::: "memory");
  __builtin_amdgcn_sched_barrier(0);
  __builtin_amdgcn_s_setprio(1);
#pragma unroll
  for (int i = 0; i < 4; ++i)
#pragma unroll
    for (int j = 0; j < 4; ++j)
      acc[i][j] = __builtin_amdgcn_mfma_f32_16x16x32_bf16(afL[i], bf[j], acc[i][j], 0, 0, 0);
  __builtin_amdgcn_s_setprio(0);
  __builtin_amdgcn_s_barrier();

  // ---------------- ph1: acc[4..7][*] x k-half0 ----------------
#pragma unroll
  for (int i = 0; i < 4; ++i)
    afH[i] = *(const short8*)(Lr + base + aBase + 4096 + i * 1024);
  if (kt < 7) stgB(b0, gTh, L, ldsW, BB ^ 1, kt + 1, 1);
  __builtin_amdgcn_s_barrier();
  asm volatile("s_waitcnt lgkmcnt(0)" ::: "memory");
  __builtin_amdgcn_sched_barrier(0);
  __builtin_amdgcn_s_setprio(1);
#pragma unroll
  for (int i = 0; i < 4; ++i)
#pragma unroll
    for (int j = 0; j < 4; ++j)
      acc[4 + i][j] = __builtin_amdgcn_mfma_f32_16x16x32_bf16(afH[i], bf[j], acc[4 + i][j], 0, 0, 0);
  __builtin_amdgcn_s_setprio(0);
  if (kt < 7) asm volatile("s_waitcnt vmcnt(8)" ::: "memory");
  else        asm volatile("s_waitcnt vmcnt(0)" ::: "memory");
  __builtin_amdgcn_sched_barrier(0);
  __builtin_amdgcn_s_barrier();

  // ---------------- ph2: acc[0..3][*] x k-half1 ----------------
#pragma unroll
  for (int i = 0; i < 4; ++i)
    afL[i] = *(const short8*)(Lr + base + 16384 + aBase + i * 1024);
#pragma unroll
  for (int j = 0; j < 4; ++j)
    bf[j] = *(const short8*)(Lr + base + 16384 + bBase + j * 1024);
  if (kt < 6) stgA(a0, gTh, L, ldsW, BB, kt + 2, 0);
  __builtin_amdgcn_s_barrier();
  asm volatile("s_waitcnt lgkmcnt(0)" ::: "memory");
  __builtin_amdgcn_sched_barrier(0);
  __builtin_amdgcn_s_setprio(1);
#pragma unroll
  for (int i = 0; i < 4; ++i)
#pragma unroll
    for (int j = 0; j < 4; ++j)
      acc[i][j] = __builtin_amdgcn_mfma_f32_16x16x32_bf16(afL[i], bf[j], acc[i][j], 0, 0, 0);
  __builtin_amdgcn_s_setprio(0);
  __builtin_amdgcn_s_barrier();

  // ---------------- ph3: acc[4..7][*] x k-half1 ----------------
#pragma unroll
  for (int i = 0; i < 4; ++i)
    afH[i] = *(const short8*)(Lr + base + 16384 + aBase + 4096 + i * 1024);
  if (kt < 6) stgB(b0, gTh, L, ldsW, BB, kt + 2, 0);
  __builtin_amdgcn_s_barrier();
  asm volatile("s_waitcnt lgkmcnt(0)" ::: "memory");
  __builtin_amdgcn_sched_barrier(0);
  __builtin_amdgcn_s_setprio(1);
#pragma unroll
  for (int i = 0; i < 4; ++i)
#pragma unroll
    for (int j = 0; j < 4; ++j)
      acc[4 + i][j] = __builtin_amdgcn_mfma_f32_16x16x32_bf16(afH[i], bf[j], acc[4 + i][j], 0, 0, 0);
  __builtin_amdgcn_s_setprio(0);
  if (kt < 6)       asm volatile("s_waitcnt vmcnt(8)" ::: "memory");
  else if (kt == 6) asm volatile("s_waitcnt vmcnt(4)" ::: "memory");
  __builtin_amdgcn_sched_barrier(0);
  __builtin_amdgcn_s_barrier();
}

// ---------------------------------------------------------------------------
// GEMM: C[M,N] = A[M,512] @ BT[N,512]^T (+ bias[N]), bf16 in/out, f32 accum.
// 256x256 tile, BK=64, 8-phase schedule. Grid 1-D = (M/256)*(N/256), %8==0.
// ---------------------------------------------------------------------------
__global__ __launch_bounds__(512, 2) void gemm_bt(
    const unsigned short* __restrict__ A,
    const unsigned short* __restrict__ BT,
    const float* __restrict__ bias,
    unsigned short* __restrict__ C, int N) {
  __shared__ char LDSR[131072];  // A: 2buf x [kh][256r][64B]; B at +65536
  const int t = threadIdx.x;
  const int wave = t >> 6, lane = t & 63;
  const int wm = wave >> 2, wn = wave & 3;
  const int e = lane & 15, g = lane >> 4;

  // XCD-aware bijective swizzle (gridDim.x % 8 == 0) + row-major tile order.
  const int nTN = N >> 8;
  const int q8 = gridDim.x >> 3;
  const int lin = ((int)blockIdx.x & 7) * q8 + ((int)blockIdx.x >> 3);
  const int tm = lin / nTN;
  const int tn = lin - tm * nTN;
  const long rowBase = (long)tm * 256;
  const long colBase = (long)tn * 256;

  const unsigned short* a0 = A + (size_t)rowBase * 512;
  const unsigned short* b0 = BT + (size_t)colBase * 512;

  // staging: thread t covers LDS slot (row=t>>2 within 128-row group,
  // ccPhys=t&3); global chunk = ccPhys ^ ((row>>1)&3) [inverse swizzle].
  const size_t gTh = (size_t)(t >> 2) * 512 +
                     (size_t)(((t & 3) ^ ((t >> 3) & 3))) * 8;
  AS3 char* L = (AS3 char*)LDSR;
  const int ldsW = wave * 1024;

  // frag read offsets (byte): swizzled chunk = g ^ ((e>>1)&3)
  const int swz16 = ((g ^ ((e >> 1) & 3)) << 4);
  const char* Lr = LDSR;
  const int aBase = wm * 8192 + e * 64 + swz16;          // +mf*1024 +kh*16384
  const int bBase = 65536 + wn * 4096 + e * 64 + swz16;  // +nf*1024 +kh*16384

  floatx4 acc[8][4];
#pragma unroll
  for (int i = 0; i < 8; ++i)
#pragma unroll
    for (int j = 0; j < 4; ++j) acc[i][j] = (floatx4){0.f, 0.f, 0.f, 0.f};

  // prologue: A0k0 B0k0 A0k1 B0k1 A1k0 B1k0 (12 loads), retire first 4.
  stgA(a0, gTh, L, ldsW, 0, 0, 0); stgB(b0, gTh, L, ldsW, 0, 0, 0);
  stgA(a0, gTh, L, ldsW, 0, 0, 1); stgB(b0, gTh, L, ldsW, 0, 0, 1);
  stgA(a0, gTh, L, ldsW, 1, 1, 0); stgB(b0, gTh, L, ldsW, 1, 1, 0);
  asm volatile("s_waitcnt vmcnt(8)" ::: "memory");
  __builtin_amdgcn_sched_barrier(0);
  __builtin_amdgcn_s_barrier();

#pragma unroll 1
  for (int ktp = 0; ktp < 4; ++ktp) {
    kt_step<0>(2 * ktp,     Lr, L, a0, b0, gTh, ldsW, aBase, bBase, acc);
    kt_step<1>(2 * ktp + 1, Lr, L, a0, b0, gTh, ldsW, aBase, bBase, acc);
  }

  // safety drain (ledger says 0 outstanding here; this is free)
  asm volatile("s_waitcnt vmcnt(0) lgkmcnt(0)" ::: "memory");
  __builtin_amdgcn_sched_barrier(0);

  // epilogue: C/D layout col=lane&15, row=(lane>>4)*4+reg  [m89-verified]
  const int q4 = g << 2;
#pragma unroll
  for (int mf = 0; mf < 8; ++mf) {
    const long rowa = rowBase + wm * 128 + mf * 16 + q4;
#pragma unroll
    for (int nf = 0; nf < 4; ++nf) {
      const long col = colBase + wn * 64 + nf * 16 + e;
      const float badd = bias ? bias[col] : 0.f;
#pragma unroll
      for (int r = 0; r < 4; ++r)
        C[(size_t)(rowa + r) * N + col] = f2bf(acc[mf][nf][r] + badd);
    }
  }
}

// ---------------------------------------------------------------------------
// MFMA attention: one wave per (b,h). grid = 8192 blocks x 256 thr (4 waves).
// S^T = K.Q^T (2x2 tiles of 16x16x32, row 16 clamped), in-register softmax,
// P repacked via shfl to the K=32 A-fragment, PV from LDS-staged V.
// ---------------------------------------------------------------------------
__global__ __launch_bounds__(256) void attn_kernel(
    const unsigned short* __restrict__ qkv, unsigned short* __restrict__ o) {
  __shared__ unsigned short Vl[4][17][76];  // stride 76: bank-clean frag reads
  const int t = threadIdx.x;
  const int wave = t >> 6, lane = t & 63;
  const int wid = blockIdx.x * 4 + wave;
  const int b = wid >> 3, h = wid & 7;
  const int e = lane & 15, g = lane >> 4;

  const unsigned short* base = qkv + (size_t)b * 17 * 1536 + h * 64;

  // ---- stage V rows 0..16 into LDS (row-major, stride 76 shorts) ----
  unsigned short (*V)[76] = Vl[wave];
  for (int c = lane; c < 136; c += 64) {  // 136 = 17 rows * 8 chunks
    const int kk = c >> 3, e0 = (c & 7) << 3;
    const uint4 u = *(const uint4*)(base + (size_t)kk * 1536 + 1024 + e0);
    *(uint2*)&V[kk][e0]     = make_uint2(u.x, u.y);
    *(uint2*)&V[kk][e0 + 4] = make_uint2(u.z, u.w);
  }

  // ---- Q/K fragments direct from global (row=lane&15, k-off=8*g) ----
  const int ko = g << 3;
  const unsigned short* qrow  = base + (size_t)e * 1536;
  const unsigned short* row16 = base + (size_t)16 * 1536;
  const short8 Q0  = *(const short8*)(qrow + ko);
  const short8 Q1  = *(const short8*)(qrow + 32 + ko);
  const short8 K0  = *(const short8*)(qrow + 512 + ko);
  const short8 K1  = *(const short8*)(qrow + 512 + 32 + ko);
  const short8 Qb0 = *(const short8*)(row16 + ko);
  const short8 Qb1 = *(const short8*)(row16 + 32 + ko);
  const short8 Kb0 = *(const short8*)(row16 + 512 + ko);
  const short8 Kb1 = *(const short8*)(row16 + 512 + 32 + ko);

  // ---- S^T tiles: sT[mi][ni], mi = kk-tile (A=K), ni = j-tile (B=Q) ----
  floatx4 sT[2][2];
#pragma unroll
  for (int i = 0; i < 2; ++i)
#pragma unroll
    for (int j = 0; j < 2; ++j) sT[i][j] = (floatx4){0.f, 0.f, 0.f, 0.f};
  sT[0][0] = __builtin_amdgcn_mfma_f32_16x16x32_bf16(K0, Q0, sT[0][0], 0, 0, 0);
  sT[0][0] = __builtin_amdgcn_mfma_f32_16x16x32_bf16(K1, Q1, sT[0][0], 0, 0, 0);
  sT[0][1] = __builtin_amdgcn_mfma_f32_16x16x32_bf16(K0, Qb0, sT[0][1], 0, 0, 0);
  sT[0][1] = __builtin_amdgcn_mfma_f32_16x16x32_bf16(K1, Qb1, sT[0][1], 0, 0, 0);
  sT[1][0] = __builtin_amdgcn_mfma_f32_16x16x32_bf16(Kb0, Q0, sT[1][0], 0, 0, 0);
  sT[1][0] = __builtin_amdgcn_mfma_f32_16x16x32_bf16(Kb1, Q1, sT[1][0], 0, 0, 0);
  sT[1][1] = __builtin_amdgcn_mfma_f32_16x16x32_bf16(Kb0, Qb0, sT[1][1], 0, 0, 0);
  sT[1][1] = __builtin_amdgcn_mfma_f32_16x16x32_bf16(Kb1, Qb1, sT[1][1], 0, 0, 0);

  // ---- softmax over kk (lane holds kk=4g+r of column j=e; kk=16 in sT[1]) ----
  short8 PA[2];
#pragma unroll
  for (int ni = 0; ni < 2; ++ni) {
    float v[4];
#pragma unroll
    for (int r = 0; r < 4; ++r) v[r] = sT[0][ni][r] * 0.125f;
    const float v16 = sT[1][ni][0] * 0.125f;
    float m = fmaxf(fmaxf(v[0], v[1]), fmaxf(v[2], v[3]));
    if (g == 0) m = fmaxf(m, v16);
    m = fmaxf(m, __shfl_xor(m, 16, 64));
    m = fmaxf(m, __shfl_xor(m, 32, 64));
    float p[4], sum = 0.f;
#pragma unroll
    for (int r = 0; r < 4; ++r) { p[r] = __expf(v[r] - m); sum += p[r]; }
    float p16 = (g == 0) ? __expf(v16 - m) : 0.f;
    sum += p16;
    sum += __shfl_xor(sum, 16, 64);
    sum += __shfl_xor(sum, 32, 64);
    const float inv = 1.f / sum;
#pragma unroll
    for (int r = 0; r < 4; ++r) p[r] *= inv;
    p16 *= inv;

    const unsigned int lo = (unsigned int)f2bf(p[0]) | ((unsigned int)f2bf(p[1]) << 16);
    const unsigned int hi = (unsigned int)f2bf(p[2]) | ((unsigned int)f2bf(p[3]) << 16);
    const unsigned int w16 = (unsigned int)f2bf(p16);

    // target lane (g, jj=lane&15) needs column (ni?16:jj)'s kk = 8g..8g+7
    const int colsrc = ni ? 0 : e;
    const int s0 = colsrc + ((g & 1) << 5);
    unsigned int w0 = __shfl(lo, s0, 64);
    unsigned int w1 = __shfl(hi, s0, 64);
    unsigned int w2 = __shfl(lo, s0 + 16, 64);
    unsigned int w3 = __shfl(hi, s0 + 16, 64);
    const unsigned int a16 = __shfl(w16, colsrc, 64);
    if (g == 2) { w0 = a16; w1 = 0; w2 = 0; w3 = 0; }
    if (g == 3) { w0 = 0; w1 = 0; w2 = 0; w3 = 0; }
    union { unsigned int u[4]; short8 s; } fa;
    fa.u[0] = w0; fa.u[1] = w1; fa.u[2] = w2; fa.u[3] = w3;
    PA[ni] = fa.s;
  }

  // ---- PV: O tiles o0 (j=0..15), o1 (j=16) per e'-tile t ----
  floatx4 o0[4], o1[4];
#pragma unroll
  for (int tt = 0; tt < 4; ++tt) {
    o0[tt] = (floatx4){0.f, 0.f, 0.f, 0.f};
    o1[tt] = (floatx4){0.f, 0.f, 0.f, 0.f};
  }
#pragma unroll
  for (int tt = 0; tt < 4; ++tt) {
    const int c = tt * 16 + e;
    union { unsigned int u[4]; short8 s; } fb;
#pragma unroll
    for (int i = 0; i < 4; ++i) {
      int ka = (g << 3) + 2 * i;     // kk for element 2i
      int kb = ka + 1;
      if (ka > 16) ka = 16;
      if (kb > 16) kb = 16;
      fb.u[i] = (unsigned int)V[ka][c] | ((unsigned int)V[kb][c] << 16);
    }
    o0[tt] = __builtin_amdgcn_mfma_f32_16x16x32_bf16(PA[0], fb.s, o0[tt], 0, 0, 0);
    o1[tt] = __builtin_amdgcn_mfma_f32_16x16x32_bf16(PA[1], fb.s, o1[tt], 0, 0, 0);
  }

  // ---- store: C layout col=lane&15 (+16t), row=4g+r (+16 for o1) ----
  unsigned short* ob = o + (size_t)b * 17 * 512 + h * 64;
#pragma unroll
  for (int tt = 0; tt < 4; ++tt)
#pragma unroll
    for (int r = 0; r < 4; ++r)
      ob[(size_t)(4 * g + r) * 512 + tt * 16 + e] = f2bf(o0[tt][r]);
  if (g == 0) {
#pragma unroll
    for (int tt = 0; tt < 4; ++tt)
      ob[(size_t)16 * 512 + tt * 16 + e] = f2bf(o1[tt][0]);
  }
}

// ---------------------------------------------------------------------------
// X = LN1(src_f32 + att_bf16; g,beta f32) -> bf16. One wave per row.
// ---------------------------------------------------------------------------
__global__ __launch_bounds__(256) void ln_res_kernel(
    const float* __restrict__ a, const unsigned short* __restrict__ b,
    const float* __restrict__ g, const float* __restrict__ beta,
    unsigned short* __restrict__ out) {
  const long row = (long)blockIdx.x * 4 + (threadIdx.x >> 6);
  const int lane = threadIdx.x & 63;
  const int d0 = lane * 8;

  const float4 a0 = *(const float4*)(a + (size_t)row * 512 + d0);
  const float4 a1 = *(const float4*)(a + (size_t)row * 512 + d0 + 4);
  const float fa[8] = {a0.x, a0.y, a0.z, a0.w, a1.x, a1.y, a1.z, a1.w};
  float fb[8], vals[8];
  unpack8(*(const uint4*)(b + (size_t)row * 512 + d0), fb);
  float s = 0.f, s2 = 0.f;
#pragma unroll
  for (int i = 0; i < 8; ++i) {
    vals[i] = fa[i] + fb[i];
    s += vals[i];
    s2 += vals[i] * vals[i];
  }
  const float mean = wave_sum(s) * (1.f / 512.f);
  const float var = wave_sum(s2) * (1.f / 512.f) - mean * mean;
  const float rs = rsqrtf(var + 1e-5f);

  const float4 g0 = *(const float4*)(g + d0);
  const float4 g1 = *(const float4*)(g + d0 + 4);
  const float4 b0 = *(const float4*)(beta + d0);
  const float4 b1 = *(const float4*)(beta + d0 + 4);
  const float fg[8]  = {g0.x, g0.y, g0.z, g0.w, g1.x, g1.y, g1.z, g1.w};
  const float fbt[8] = {b0.x, b0.y, b0.z, b0.w, b1.x, b1.y, b1.z, b1.w};
  float y[8];
#pragma unroll
  for (int i = 0; i < 8; ++i) y[i] = (vals[i] - mean) * rs * fg[i] + fbt[i];
  *(uint4*)(out + (size_t)row * 512 + d0) = pack8(y);
}

// ---------------------------------------------------------------------------
// out_f32 = LN2(x + gcn + b_gcn); gcn = Adiag[j]*h0[row] + sum_nbr w*h1[b,k]
// ---------------------------------------------------------------------------
__global__ __launch_bounds__(256) void gcn_ln_kernel(
    const unsigned short* __restrict__ x, const unsigned short* __restrict__ h01,
    const float* __restrict__ Adiag, const int* __restrict__ cnt,
    const int* __restrict__ nbrk, const float* __restrict__ nbrw,
    const float* __restrict__ bgcn,
    const float* __restrict__ g, const float* __restrict__ beta,
    float* __restrict__ out) {
  const long row = (long)blockIdx.x * 4 + (threadIdx.x >> 6);
  const int lane = threadIdx.x & 63;
  const int b = (int)(row / 17);
  const int j = (int)(row - (long)b * 17);
  const int d0 = lane * 8;

  float accv[8];
  {
    const float w = Adiag[j];
    float f[8];
    unpack8(*(const uint4*)(h01 + (size_t)row * 1024 + d0), f);
#pragma unroll
    for (int i = 0; i < 8; ++i) accv[i] = w * f[i];
  }
  const int c = cnt[j];
  for (int nb = 0; nb < c; ++nb) {
    const int kk = nbrk[j * 8 + nb];
    const float w = nbrw[j * 8 + nb];
    float f[8];
    unpack8(*(const uint4*)(h01 + ((size_t)b * 17 + kk) * 1024 + 512 + d0), f);
#pragma unroll
    for (int i = 0; i < 8; ++i) accv[i] += w * f[i];
  }

  float fx[8], vals[8];
  unpack8(*(const uint4*)(x + (size_t)row * 512 + d0), fx);
  const float4 bg0 = *(const float4*)(bgcn + d0);
  const float4 bg1 = *(const float4*)(bgcn + d0 + 4);
  const float fbg[8] = {bg0.x, bg0.y, bg0.z, bg0.w, bg1.x, bg1.y, bg1.z, bg1.w};
  float s = 0.f, s2 = 0.f;
#pragma unroll
  for (int i = 0; i < 8; ++i) {
    vals[i] = fx[i] + accv[i] + fbg[i];
    s += vals[i];
    s2 += vals[i] * vals[i];
  }
  const float mean = wave_sum(s) * (1.f / 512.f);
  const float var = wave_sum(s2) * (1.f / 512.f) - mean * mean;
  const float rs = rsqrtf(var + 1e-5f);

  const float4 g0 = *(const float4*)(g + d0);
  const float4 g1 = *(const float4*)(g + d0 + 4);
  const float4 bb0 = *(const float4*)(beta + d0);
  const float4 bb1 = *(const float4*)(beta + d0 + 4);
  const float fg[8]  = {g0.x, g0.y, g0.z, g0.w, g1.x, g1.y, g1.z, g1.w};
  const float fbt[8] = {bb0.x, bb0.y, bb0.z, bb0.w, bb1.x, bb1.y, bb1.z, bb1.w};
  float4 y0, y1;
  y0.x = (vals[0] - mean) * rs * fg[0] + fbt[0];
  y0.y = (vals[1] - mean) * rs * fg[1] + fbt[1];
  y0.z = (vals[2] - mean) * rs * fg[2] + fbt[2];
  y0.w = (vals[3] - mean) * rs * fg[3] + fbt[3];
  y1.x = (vals[4] - mean) * rs * fg[4] + fbt[4];
  y1.y = (vals[5] - mean) * rs * fg[5] + fbt[5];
  y1.z = (vals[6] - mean) * rs * fg[6] + fbt[6];
  y1.w = (vals[7] - mean) * rs * fg[7] + fbt[7];
  *(float4*)(out + (size_t)row * 512 + d0) = y0;
  *(float4*)(out + (size_t)row * 512 + d0 + 4) = y1;
}

// ---------------------------------------------------------------------------
// Weight transposes (f32 in) into [N][K] bf16 layouts
// ---------------------------------------------------------------------------
__global__ __launch_bounds__(256) void prep_transpose(
    const float* __restrict__ Wq, const float* __restrict__ Wk,
    const float* __restrict__ Wv, const float* __restrict__ Wo,
    const float* __restrict__ Wg,
    unsigned short* __restrict__ WT1, unsigned short* __restrict__ WT2,
    unsigned short* __restrict__ WT3) {
  const int idx = blockIdx.x * 256 + threadIdx.x;
  if (idx < 786432) {  // WT1[n][k]: n = which*512 + h*64 + e
    const int n = idx >> 9, k = idx & 511;
    const int which = n >> 9, nn = n & 511;
    const int hh = nn >> 6, e = nn & 63;
    const float* W = (which == 0) ? Wq : (which == 1) ? Wk : Wv;
    WT1[idx] = f2bf(W[hh * 32768 + k * 64 + e]);
  } else if (idx < 786432 + 262144) {  // WT2[n][k] = Wo[k][n]
    const int i2 = idx - 786432;
    const int n = i2 >> 9, k = i2 & 511;
    WT2[i2] = f2bf(Wo[k * 512 + n]);
  } else {  // WT3[n'][k] = Wg[which][k][n]
    const int i3 = idx - 1048576;
    const int n = i3 >> 9, k = i3 & 511;
    const int which = n >> 9, nn = n & 511;
    WT3[i3] = f2bf(Wg[which * 262144 + k * 512 + nn]);
  }
}

// ---------------------------------------------------------------------------
// bias concat (f32) + adjacency row-softmax + neighbor lists
// ---------------------------------------------------------------------------
__global__ __launch_bounds__(256) void prep_small(
    const float* __restrict__ bq, const float* __restrict__ bk,
    const float* __restrict__ bv, const float* __restrict__ bo,
    const float* __restrict__ e, const int* __restrict__ rows,
    const int* __restrict__ cols, int nnz,
    float* __restrict__ bias1, float* __restrict__ bias2,
    float* __restrict__ Adiag, int* __restrict__ cnt,
    int* __restrict__ nbrk, float* __restrict__ nbrw) {
  const int t = threadIdx.x;
  for (int i = t; i < 1536; i += 256)
    bias1[i] = (i < 512) ? bq[i] : (i < 1024) ? bk[i - 512] : bv[i - 1024];
  for (int i = t; i < 512; i += 256) bias2[i] = bo[i];
  if (t < 17) {
    float m = -1e30f;
    for (int i = 0; i < nnz; ++i)
      if (rows[i] == t) m = fmaxf(m, e[i]);
    float s = 0.f;
    for (int i = 0; i < nnz; ++i)
      if (rows[i] == t) s += __expf(e[i] - m);
    const float inv = 1.f / s;
    int c = 0;
    for (int i = 0; i < nnz; ++i)
      if (rows[i] == t) {
        const float w = __expf(e[i] - m) * inv;
        const int kk = cols[i];
        if (kk == t) Adiag[t] = w;
        else { nbrk[t * 8 + c] = kk; nbrw[t * 8 + c] = w; ++c; }
      }
    cnt[t] = c;
  }
}

// ---------------------------------------------------------------------------
extern "C" void kernel_launch(void* const* d_in, const int* in_sizes, int n_in,
                              void* d_out, int out_size, void* d_ws, size_t ws_size,
                              hipStream_t stream) {
  const float* src = (const float*)d_in[0];
  const float* Wq  = (const float*)d_in[1];
  const float* bq  = (const float*)d_in[2];
  const float* Wk  = (const float*)d_in[3];
  const float* bk  = (const float*)d_in[4];
  const float* Wv  = (const float*)d_in[5];
  const float* bv  = (const float*)d_in[6];
  const float* Wo  = (const float*)d_in[7];
  const float* bo  = (const float*)d_in[8];
  const float* ln1g = (const float*)d_in[9];
  const float* ln1b = (const float*)d_in[10];
  const float* Wg  = (const float*)d_in[11];
  const float* eg  = (const float*)d_in[12];
  const float* bg  = (const float*)d_in[13];
  const float* ln2g = (const float*)d_in[14];
  const float* ln2b = (const float*)d_in[15];
  const int* mrows = (const int*)d_in[16];
  const int* mcols = (const int*)d_in[17];
  const int nnz = in_sizes[16];

  float* out = (float*)d_out;
  char* ws = (char*)d_ws;

  unsigned short* WT1 = (unsigned short*)(ws + 0x0000000);
  unsigned short* WT2 = (unsigned short*)(ws + 0x0180000);
  unsigned short* WT3 = (unsigned short*)(ws + 0x0200000);
  float* bias1 = (float*)(ws + 0x0300000);
  float* bias2 = (float*)(ws + 0x0302000);
  float* Adiag = (float*)(ws + 0x0303000);
  int* cnt     = (int*)(ws + 0x0303100);
  int* nbrk    = (int*)(ws + 0x0303200);
  float* nbrw  = (float*)(ws + 0x0303600);
  unsigned short* SRCB = (unsigned short*)(ws + 0x0400000);
  unsigned short* QKV  = (unsigned short*)(ws + 0x4800000);
  unsigned short* O    = (unsigned short*)(ws + 0x0400000);  // after SRCB dead
  unsigned short* ATT  = (unsigned short*)(ws + 0x4800000);  // after QKV dead
  unsigned short* X    = (unsigned short*)(ws + 0x8C00000);
  unsigned short* H01  = (unsigned short*)(ws + 0x0400000);  // after O/ATT dead

  (void)n_in; (void)out_size; (void)ws_size;

  convert_src<<<17408, 256, 0, stream>>>(src, SRCB);
  prep_transpose<<<6144, 256, 0, stream>>>(Wq, Wk, Wv, Wo, Wg, WT1, WT2, WT3);
  prep_small<<<1, 256, 0, stream>>>(bq, bk, bv, bo, eg, mrows, mcols, nnz,
                                    bias1, bias2, Adiag, cnt, nbrk, nbrw);
  // 1-D grids: (M/256)*(N/256) = 272*{6,2,4}, all divisible by 8.
  gemm_bt<<<1632, 512, 0, stream>>>(SRCB, WT1, bias1, QKV, 1536);
  attn_kernel<<<8192, 256, 0, stream>>>(QKV, O);
  gemm_bt<<<544, 512, 0, stream>>>(O, WT2, bias2, ATT, 512);
  ln_res_kernel<<<17408, 256, 0, stream>>>(src, ATT, ln1g, ln1b, X);
  gemm_bt<<<1088, 512, 0, stream>>>(X, WT3, nullptr, H01, 1024);
  gcn_ln_kernel<<<17408, 256, 0, stream>>>(X, H01, Adiag, cnt, nbrk, nbrw, bg,
                                           ln2g, ln2b, out);
}